// Round 7
// baseline (23435.080 us; speedup 1.0000x reference)
//
#include <hip/hip_runtime.h>
#include <cstdint>
#include <cstddef>

#define B_SZ 64
#define T_SZ 1536
#define C_SZ 256
#define H_SZ 512
#define G4H  2048
#define POLL_BUDGET 50000000

typedef __attribute__((ext_vector_type(8))) short short8;
typedef __attribute__((ext_vector_type(4))) float f32x4;

__device__ __forceinline__ unsigned short f2bf_rne(float f) {
    unsigned u = __float_as_uint(f);
    unsigned r = (u + 0x7FFF + ((u >> 16) & 1)) >> 16;
    return (unsigned short)r;
}
__device__ __forceinline__ float bf2f(unsigned short b) {
    return __uint_as_float(((unsigned)b) << 16);
}
__device__ __forceinline__ float sigmoid_f(float x) {
    return 1.f / (1.f + __expf(-x));
}
__device__ __forceinline__ float tanh_f(float x) {
    return 1.f - 2.f / (__expf(2.f * x) + 1.f);
}

// ---------------------------------------------------------------------------
// Input GEMM (verified R2-R6). Output [tlen][B][4H].
// ---------------------------------------------------------------------------
template<int AMODE>
__global__ __launch_bounds__(256)
void gemm_gx(const float* __restrict__ A, const float* __restrict__ W,
             const float* __restrict__ bias1, const float* __restrict__ bias2,
             float* __restrict__ gx, int K, int astride_b, int t0g, int tlen)
{
    __shared__ float a_s[8][132];
    __shared__ float b_s[8][132];
    const int tb = blockIdx.x, nb = blockIdx.y, b = blockIdx.z;
    const int tloc = tb * 128;
    const int tglb = t0g + tloc;
    const int r0 = nb * 128;
    const float* Ab = A + (size_t)b * astride_b;
    const int tid = threadIdx.x;
    const int tx = tid & 15, ty = tid >> 4;
    float acc[8][8] = {};

    for (int k0 = 0; k0 < K; k0 += 8) {
        if (AMODE == 0) {
            const int row = tid >> 5;
            const int col = (tid & 31) << 2;
            const float4 v = *(const float4*)(Ab + (size_t)(k0 + row) * T_SZ + tglb + col);
            *(float4*)&a_s[row][col] = v;
        } else {
            const int row  = tid >> 1;
            const int half = (tid & 1) << 2;
            const float4 v = *(const float4*)(Ab + (size_t)(tglb + row) * H_SZ + k0 + half);
            a_s[half + 0][row] = v.x; a_s[half + 1][row] = v.y;
            a_s[half + 2][row] = v.z; a_s[half + 3][row] = v.w;
        }
        {
            const int row  = tid >> 1;
            const int half = (tid & 1) << 2;
            const float4 v = *(const float4*)(W + (size_t)(r0 + row) * K + k0 + half);
            b_s[half + 0][row] = v.x; b_s[half + 1][row] = v.y;
            b_s[half + 2][row] = v.z; b_s[half + 3][row] = v.w;
        }
        __syncthreads();
        #pragma unroll
        for (int kk = 0; kk < 8; ++kk) {
            float4 a0 = *(const float4*)&a_s[kk][tx * 8];
            float4 a1 = *(const float4*)&a_s[kk][tx * 8 + 4];
            float4 w0 = *(const float4*)&b_s[kk][ty * 8];
            float4 w1 = *(const float4*)&b_s[kk][ty * 8 + 4];
            float av[8] = {a0.x, a0.y, a0.z, a0.w, a1.x, a1.y, a1.z, a1.w};
            float wv[8] = {w0.x, w0.y, w0.z, w0.w, w1.x, w1.y, w1.z, w1.w};
            #pragma unroll
            for (int i = 0; i < 8; ++i)
                #pragma unroll
                for (int j = 0; j < 8; ++j)
                    acc[i][j] += wv[i] * av[j];
        }
        __syncthreads();
    }
    float bs[8];
    #pragma unroll
    for (int i = 0; i < 8; ++i)
        bs[i] = bias1[r0 + ty * 8 + i] + bias2[r0 + ty * 8 + i];
    #pragma unroll
    for (int j = 0; j < 8; ++j) {
        float* dst = gx + ((size_t)(tloc + tx * 8 + j) * B_SZ + b) * G4H + r0 + ty * 8;
        float4 o0 = {acc[0][j] + bs[0], acc[1][j] + bs[1], acc[2][j] + bs[2], acc[3][j] + bs[3]};
        float4 o1 = {acc[4][j] + bs[4], acc[5][j] + bs[5], acc[6][j] + bs[6], acc[7][j] + bs[7]};
        *(float4*)dst = o0; *(float4*)(dst + 4) = o1;
    }
}

// ---------------------------------------------------------------------------
__global__ void wsplit(const float* __restrict__ w,
                       unsigned short* __restrict__ hi,
                       unsigned short* __restrict__ lo, int n)
{
    const int i = blockIdx.x * 256 + threadIdx.x;
    if (i < n) {
        const float v = w[i];
        const unsigned short h = f2bf_rne(v);
        hi[i] = h;
        lo[i] = f2bf_rne(v - bf2f(h));
    }
}

// ---------------------------------------------------------------------------
// MFMA LSTM scan v5. Self-validating exchange as v3/v4 (u32 = hi<<16 |
// lo&0xFFFC | cbits, cbits = ((t>>1)&1)|2; data load IS the sync).
// New in v5 (LDS-bandwidth attack):
//  * wave (tg 0..3, kh 0..1) computes TWO 16-row A-tiles (32 gate rows =
//    8 units x 4 gates) over K-half kh (256). B(h) reads per wave drop
//    32KB -> 16KB; per WG 256KB -> 128KB per step.
//  * per-step partial-gate exchange: wave keeps tile tau==kh in regs,
//    writes tile tau==1-kh partials to gate_lds; after barrier each lane
//    updates (batch m16, unit w*32+tg*8+kh*4+q) with own + peer + gx.
//    (C-row q*4+p <-> gate p, unit-in-tile q: in-lane 4-gate property kept.)
//  * h_out(t-1) store + gx(t+1) prefetch issued AFTER the poll loop, so
//    the poll's vmcnt covers only staging loads (+cheap hex-store ack).
// Grid = 64 WGs x 512 thr: WG (grp=bid&3: 16 batches, w=bid>>2: 32 units).
// ---------------------------------------------------------------------------
__global__ __launch_bounds__(512, 2)
void lstm_scan_mfma(const float* __restrict__ gx,            // [tlen][B][4H]
                    const unsigned short* __restrict__ Whi,  // [4H][H] bf16 bits
                    const unsigned short* __restrict__ Wlo,
                    float* __restrict__ h_out,               // [B][T][H]
                    unsigned int* hex,                       // [2][4][16][512] u32
                    float* __restrict__ c_state,             // [B][H]
                    int t0, int steps, int tlen)
{
    __shared__ __align__(16) char hHI[2][16384];  // [pb][16 b][512 u] bf16, swizzled
    __shared__ __align__(16) char hLO[2][16384];
    __shared__ float gate_lds[4][2][16][18];      // [tg][tile][row][col], padded

    const int tid  = threadIdx.x;
    const int grp  = blockIdx.x & 3;
    const int w    = blockIdx.x >> 2;     // 0..15
    const int wv   = tid >> 6;            // wave 0..7
    const int tg   = wv & 3;              // unit-group (8 units)
    const int kh   = wv >> 2;             // K-half
    const int lane = tid & 63;
    const int m16  = lane & 15;           // batch col / A-row
    const int q    = lane >> 4;           // k-subgroup / unit-in-tile

    // --- pin W: A-row r=m16 <-> (gate=r&3, du=r>>2); 2 tiles x K-half
    short8 whi[2][8], wlo[2][8];
    #pragma unroll
    for (int tau = 0; tau < 2; ++tau) {
        const size_t rowbase =
            (size_t)((m16 & 3) * H_SZ + w * 32 + tg * 8 + tau * 4 + (m16 >> 2)) * H_SZ
            + kh * 256 + q * 8;
        #pragma unroll
        for (int kk = 0; kk < 8; ++kk) {
            whi[tau][kk] = *(const short8*)(Whi + rowbase + kk * 32);
            wlo[tau][kk] = *(const short8*)(Wlo + rowbase + kk * 32);
        }
    }

    // this lane updates (batch m16, unit of tile tau==kh, du=q)
    const int ug = w * 32 + tg * 8 + kh * 4 + q;
    const int bg = grp * 16 + m16;
    float c_val = (t0 > 0) ? c_state[(size_t)bg * H_SZ + ug] : 0.f;
    float h_prev = 0.f;

    const float* gxp = gx + (size_t)bg * G4H + ug;   // + tt*B*4H + p*512
    const int swz = (m16 & 7) << 4;
    int polls = 0;

    float gxc[4];
    #pragma unroll
    for (int p = 0; p < 4; ++p) gxc[p] = gxp[p * H_SZ];

    for (int tt = 0; tt < steps; ++tt) {
        const int t  = t0 + tt;
        const int pb = tt & 1;
        char* dHI = hHI[pb];
        char* dLO = hLO[pb];

        // ---- staging loads + poll (serial path: only these in the vmcnt wait)
        unsigned v[16];
        if (t > 0) {
            const unsigned cexp = ((unsigned)((t - 1) >> 1) & 1u) | 2u;
            const unsigned int* src = hex + ((size_t)((t - 1) & 1) * 4 + grp) * 8192 + tid;
            #pragma unroll
            for (int m = 0; m < 16; ++m)
                v[m] = __hip_atomic_load(src + m * 512, __ATOMIC_RELAXED,
                                         __HIP_MEMORY_SCOPE_AGENT);
            for (;;) {
                bool ok = true;
                #pragma unroll
                for (int m = 0; m < 16; ++m)
                    if ((v[m] & 3u) != cexp) {
                        v[m] = __hip_atomic_load(src + m * 512, __ATOMIC_RELAXED,
                                                 __HIP_MEMORY_SCOPE_AGENT);
                        ok = false;
                    }
                if (ok) break;
                if (++polls > POLL_BUDGET) break;   // hang safety valve
            }
            asm volatile("" ::: "memory");   // pin off-path ops below the poll
        }

        // ---- off-critical-path: h_out(t-1) store, gx(t+1) prefetch
        if (tt > 0)
            h_out[((size_t)bg * T_SZ + (t - 1)) * H_SZ + ug] = h_prev;
        float gxn[4] = {0.f, 0.f, 0.f, 0.f};
        if (tt + 1 < steps) {
            const float* gn = gxp + (size_t)(tt + 1) * (B_SZ * G4H);
            #pragma unroll
            for (int p = 0; p < 4; ++p) gxn[p] = gn[p * H_SZ];
        }

        // ---- stage into swizzled LDS buf[pb]
        if (t == 0) {
            const float4 z = {0.f, 0.f, 0.f, 0.f};
            *(float4*)(dHI + tid * 16)        = z;
            *(float4*)(dHI + tid * 16 + 8192) = z;
            *(float4*)(dLO + tid * 16)        = z;
            *(float4*)(dLO + tid * 16 + 8192) = z;
        } else {
            #pragma unroll
            for (int m = 0; m < 16; ++m) {
                const int off = ((m << 10) + 2 * tid) ^ ((m & 7) << 4);
                *(unsigned short*)(dHI + off) = (unsigned short)(v[m] >> 16);
                *(unsigned short*)(dLO + off) = (unsigned short)(v[m] & 0xFFFCu);
            }
        }
        __syncthreads();   // B1: h staged

        // ---- 3-product MFMA: 2 tiles x K-half (corrections share one acc)
        f32x4 mn[2] = {{0,0,0,0},{0,0,0,0}};
        f32x4 cr[2] = {{0,0,0,0},{0,0,0,0}};
        const char* hb = dHI + (m16 << 10);
        const char* lb = dLO + (m16 << 10);
        #pragma unroll
        for (int kk = 0; kk < 8; ++kk) {
            const int off = (kh * 512 + kk * 64 + q * 16) ^ swz;
            const short8 hh = *(const short8*)(hb + off);
            const short8 hl = *(const short8*)(lb + off);
            #pragma unroll
            for (int tau = 0; tau < 2; ++tau) {
                mn[tau] = __builtin_amdgcn_mfma_f32_16x16x32_bf16(whi[tau][kk], hh, mn[tau], 0, 0, 0);
                cr[tau] = __builtin_amdgcn_mfma_f32_16x16x32_bf16(whi[tau][kk], hl, cr[tau], 0, 0, 0);
                cr[tau] = __builtin_amdgcn_mfma_f32_16x16x32_bf16(wlo[tau][kk], hh, cr[tau], 0, 0, 0);
            }
        }

        // ---- exchange partials of the tile we do NOT update (tau = 1-kh)
        #pragma unroll
        for (int p = 0; p < 4; ++p)
            gate_lds[tg][1 - kh][q * 4 + p][m16] = mn[1 - kh][p] + cr[1 - kh][p];
        __syncthreads();   // B2: partials ready

        // ---- in-lane update (own half of tile kh + peer half + gx)
        {
            float gsum[4];
            #pragma unroll
            for (int p = 0; p < 4; ++p)
                gsum[p] = mn[kh][p] + cr[kh][p]
                        + gate_lds[tg][kh][q * 4 + p][m16] + gxc[p];
            const float si = sigmoid_f(gsum[0]);
            const float sf = sigmoid_f(gsum[1]);
            const float tc = tanh_f(gsum[2]);
            const float so = sigmoid_f(gsum[3]);
            c_val = sf * c_val + si * tc;
            const float h = so * tanh_f(c_val);
            const unsigned hb16 = f2bf_rne(h);
            const unsigned lb16 = (unsigned)f2bf_rne(h - bf2f((unsigned short)hb16)) & 0xFFFCu;
            const unsigned cb   = ((unsigned)(t >> 1) & 1u) | 2u;
            __hip_atomic_store(hex + ((size_t)(t & 1) * 4 + grp) * 8192 + m16 * 512 + ug,
                               (hb16 << 16) | lb16 | cb,
                               __ATOMIC_RELAXED, __HIP_MEMORY_SCOPE_AGENT);
            h_prev = h;
        }
        #pragma unroll
        for (int p = 0; p < 4; ++p) gxc[p] = gxn[p];
    }
    // deferred last h_out store + cross-chunk c carry
    h_out[((size_t)bg * T_SZ + (t0 + steps - 1)) * H_SZ + ug] = h_prev;
    if (t0 + steps < T_SZ)
        c_state[(size_t)bg * H_SZ + ug] = c_val;
}

// Beacon: surfaces ws_size (MiB) through the absmax error if ws is too small.
__global__ void debug_ws_beacon(float* out, float v)
{
    if (threadIdx.x == 0 && blockIdx.x == 0) out[0] = v;
}

// ---------------------------------------------------------------------------
extern "C" void kernel_launch(void* const* d_in, const int* in_sizes, int n_in,
                              void* d_out, int out_size, void* d_ws, size_t ws_size,
                              hipStream_t stream)
{
    const float* x    = (const float*)d_in[0];
    const float* Wih0 = (const float*)d_in[1];
    const float* Whh0 = (const float*)d_in[2];
    const float* bih0 = (const float*)d_in[3];
    const float* bhh0 = (const float*)d_in[4];
    const float* Wih1 = (const float*)d_in[5];
    const float* Whh1 = (const float*)d_in[6];
    const float* bih1 = (const float*)d_in[7];
    const float* bhh1 = (const float*)d_in[8];
    float* out = (float*)d_out;

    const size_t hexB  = (size_t)2 * 4 * 16 * H_SZ * 4;   // 256 KiB
    const size_t cstB  = (size_t)B_SZ * H_SZ * 4;         // 128 KiB
    const size_t wB    = (size_t)G4H * H_SZ * 2;          // 2 MiB per matrix
    const size_t fixed = hexB + cstB + 4 * wB;

    static const int opts[] = {1536, 768, 512, 384, 256, 128};
    int T_CHUNK = 0;
    for (int i = 0; i < 6; ++i) {
        const size_t need = (size_t)B_SZ * G4H * opts[i] * 4 + fixed;
        if (need <= ws_size) { T_CHUNK = opts[i]; break; }
    }
    if (T_CHUNK == 0) {
        debug_ws_beacon<<<1, 1, 0, stream>>>(out, (float)(ws_size >> 20));
        return;
    }

    char* ws = (char*)d_ws;
    const size_t gxB = (size_t)B_SZ * G4H * T_CHUNK * 4;
    float*          gx      = (float*)ws;
    unsigned int*   hex     = (unsigned int*)(ws + gxB);
    float*          c_state = (float*)(ws + gxB + hexB);
    unsigned short* whi0    = (unsigned short*)(ws + gxB + hexB + cstB);
    unsigned short* wlo0    = whi0 + G4H * H_SZ;
    unsigned short* whi1    = wlo0 + G4H * H_SZ;
    unsigned short* wlo1    = whi1 + G4H * H_SZ;

    const int nW = G4H * H_SZ;
    wsplit<<<(nW + 255) / 256, 256, 0, stream>>>(Whh0, whi0, wlo0, nW);
    wsplit<<<(nW + 255) / 256, 256, 0, stream>>>(Whh1, whi1, wlo1, nW);

    const dim3 ggrid(T_CHUNK / 128, G4H / 128, B_SZ);

    // layer 0
    hipMemsetAsync(hex, 0, hexB, stream);   // cbits bit1=0 -> never valid
    for (int t0 = 0; t0 < T_SZ; t0 += T_CHUNK) {
        gemm_gx<0><<<ggrid, 256, 0, stream>>>(x, Wih0, bih0, bhh0, gx, C_SZ,
                                              C_SZ * T_SZ, t0, T_CHUNK);
        lstm_scan_mfma<<<64, 512, 0, stream>>>(gx, whi0, wlo0, out, hex,
                                               c_state, t0, T_CHUNK, T_CHUNK);
    }
    // layer 1
    hipMemsetAsync(hex, 0, hexB, stream);   // kill layer-0 cbits
    for (int t0 = 0; t0 < T_SZ; t0 += T_CHUNK) {
        gemm_gx<1><<<ggrid, 256, 0, stream>>>(out, Wih1, bih1, bhh1, gx, H_SZ,
                                              T_SZ * H_SZ, t0, T_CHUNK);
        lstm_scan_mfma<<<64, 512, 0, stream>>>(gx, whi1, wlo1, out, hex,
                                               c_state, t0, T_CHUNK, T_CHUNK);
    }
}

// Round 8
// 22992.831 us; speedup vs baseline: 1.0192x; 1.0192x over previous
//
#include <hip/hip_runtime.h>
#include <cstdint>
#include <cstddef>

#define B_SZ 64
#define T_SZ 1536
#define C_SZ 256
#define H_SZ 512
#define G4H  2048
#define POLL_BUDGET 50000000

typedef __attribute__((ext_vector_type(8))) short short8;
typedef __attribute__((ext_vector_type(4))) float f32x4;

__device__ __forceinline__ unsigned short f2bf_rne(float f) {
    unsigned u = __float_as_uint(f);
    unsigned r = (u + 0x7FFF + ((u >> 16) & 1)) >> 16;
    return (unsigned short)r;
}
__device__ __forceinline__ float bf2f(unsigned short b) {
    return __uint_as_float(((unsigned)b) << 16);
}
__device__ __forceinline__ float sigmoid_f(float x) {
    return 1.f / (1.f + __expf(-x));
}
__device__ __forceinline__ float tanh_f(float x) {
    return 1.f - 2.f / (__expf(2.f * x) + 1.f);
}

// ---------------------------------------------------------------------------
// Input GEMM (verified R2-R7). Output [tlen][B][4H].
// ---------------------------------------------------------------------------
template<int AMODE>
__global__ __launch_bounds__(256)
void gemm_gx(const float* __restrict__ A, const float* __restrict__ W,
             const float* __restrict__ bias1, const float* __restrict__ bias2,
             float* __restrict__ gx, int K, int astride_b, int t0g, int tlen)
{
    __shared__ float a_s[8][132];
    __shared__ float b_s[8][132];
    const int tb = blockIdx.x, nb = blockIdx.y, b = blockIdx.z;
    const int tloc = tb * 128;
    const int tglb = t0g + tloc;
    const int r0 = nb * 128;
    const float* Ab = A + (size_t)b * astride_b;
    const int tid = threadIdx.x;
    const int tx = tid & 15, ty = tid >> 4;
    float acc[8][8] = {};

    for (int k0 = 0; k0 < K; k0 += 8) {
        if (AMODE == 0) {
            const int row = tid >> 5;
            const int col = (tid & 31) << 2;
            const float4 v = *(const float4*)(Ab + (size_t)(k0 + row) * T_SZ + tglb + col);
            *(float4*)&a_s[row][col] = v;
        } else {
            const int row  = tid >> 1;
            const int half = (tid & 1) << 2;
            const float4 v = *(const float4*)(Ab + (size_t)(tglb + row) * H_SZ + k0 + half);
            a_s[half + 0][row] = v.x; a_s[half + 1][row] = v.y;
            a_s[half + 2][row] = v.z; a_s[half + 3][row] = v.w;
        }
        {
            const int row  = tid >> 1;
            const int half = (tid & 1) << 2;
            const float4 v = *(const float4*)(W + (size_t)(r0 + row) * K + k0 + half);
            b_s[half + 0][row] = v.x; b_s[half + 1][row] = v.y;
            b_s[half + 2][row] = v.z; b_s[half + 3][row] = v.w;
        }
        __syncthreads();
        #pragma unroll
        for (int kk = 0; kk < 8; ++kk) {
            float4 a0 = *(const float4*)&a_s[kk][tx * 8];
            float4 a1 = *(const float4*)&a_s[kk][tx * 8 + 4];
            float4 w0 = *(const float4*)&b_s[kk][ty * 8];
            float4 w1 = *(const float4*)&b_s[kk][ty * 8 + 4];
            float av[8] = {a0.x, a0.y, a0.z, a0.w, a1.x, a1.y, a1.z, a1.w};
            float wv[8] = {w0.x, w0.y, w0.z, w0.w, w1.x, w1.y, w1.z, w1.w};
            #pragma unroll
            for (int i = 0; i < 8; ++i)
                #pragma unroll
                for (int j = 0; j < 8; ++j)
                    acc[i][j] += wv[i] * av[j];
        }
        __syncthreads();
    }
    float bs[8];
    #pragma unroll
    for (int i = 0; i < 8; ++i)
        bs[i] = bias1[r0 + ty * 8 + i] + bias2[r0 + ty * 8 + i];
    #pragma unroll
    for (int j = 0; j < 8; ++j) {
        float* dst = gx + ((size_t)(tloc + tx * 8 + j) * B_SZ + b) * G4H + r0 + ty * 8;
        float4 o0 = {acc[0][j] + bs[0], acc[1][j] + bs[1], acc[2][j] + bs[2], acc[3][j] + bs[3]};
        float4 o1 = {acc[4][j] + bs[4], acc[5][j] + bs[5], acc[6][j] + bs[6], acc[7][j] + bs[7]};
        *(float4*)dst = o0; *(float4*)(dst + 4) = o1;
    }
}

// ---------------------------------------------------------------------------
__global__ void wsplit(const float* __restrict__ w,
                       unsigned short* __restrict__ hi,
                       unsigned short* __restrict__ lo, int n)
{
    const int i = blockIdx.x * 256 + threadIdx.x;
    if (i < n) {
        const float v = w[i];
        const unsigned short h = f2bf_rne(v);
        hi[i] = h;
        lo[i] = f2bf_rne(v - bf2f(h));
    }
}

// ---------------------------------------------------------------------------
// MFMA LSTM scan v6 = R6 structure (one barrier, in-lane update) +
// R7 ordering (h_out store & gx prefetch after the poll) + W TRULY pinned.
// R6/R7 ran with VGPR_Count=116 < the 128 regs W needs -> the compiler was
// rematerializing W from L2/L3 EVERY STEP (~256KB/CU/step, ~4.5k cy) —
// the dominant hidden cost. The asm "+v" barrier below makes each fragment's
// value opaque, forcing true register residency (~200 VGPR, fits 2 waves/EU).
// Self-validating exchange unchanged: u32 = hi<<16 | lo&0xFFFC | cbits,
// cbits = ((t>>1)&1)|2; the data load IS the sync.
// Grid = 64 WGs x 512 thr: WG (grp=bid&3: 16 batches, w=bid>>2: 32 units).
// ---------------------------------------------------------------------------
__global__ __launch_bounds__(512, 2)
void lstm_scan_mfma(const float* __restrict__ gx,            // [tlen][B][4H]
                    const unsigned short* __restrict__ Whi,  // [4H][H] bf16 bits
                    const unsigned short* __restrict__ Wlo,
                    float* __restrict__ h_out,               // [B][T][H]
                    unsigned int* hex,                       // [2][4][16][512] u32
                    float* __restrict__ c_state,             // [B][H]
                    int t0, int steps, int tlen)
{
    __shared__ __align__(16) char hHI[2][16384];  // [pb][16 b][512 u] bf16, swizzled
    __shared__ __align__(16) char hLO[2][16384];

    const int tid  = threadIdx.x;
    const int grp  = blockIdx.x & 3;
    const int w    = blockIdx.x >> 2;     // 0..15
    const int wv   = tid >> 6;            // wave 0..7
    const int lane = tid & 63;
    const int m16  = lane & 15;           // batch col / A-tile row
    const int q    = lane >> 4;           // k-subgroup / unit-in-wave

    // --- pin W: A-tile row r = m16 <-> (gate g = r&3, unit du = r>>2)
    short8 whi[16], wlo[16];
    {
        const size_t rowbase =
            (size_t)((m16 & 3) * H_SZ + w * 32 + wv * 4 + (m16 >> 2)) * H_SZ + q * 8;
        #pragma unroll
        for (int kk = 0; kk < 16; ++kk) {
            whi[kk] = *(const short8*)(Whi + rowbase + kk * 32);
            wlo[kk] = *(const short8*)(Wlo + rowbase + kk * 32);
        }
    }
    // Force true VGPR residency: values become opaque to the compiler, so it
    // cannot re-load ("rematerialize") W from memory inside the t-loop.
    #pragma unroll
    for (int kk = 0; kk < 16; ++kk) {
        asm volatile("" : "+v"(whi[kk]));
        asm volatile("" : "+v"(wlo[kk]));
    }

    // this lane's (batch, unit): C/D col=m16, row=q*4+p <-> gate p, unit q
    const int ug = w * 32 + wv * 4 + q;
    const int bg = grp * 16 + m16;
    float c_val = (t0 > 0) ? c_state[(size_t)bg * H_SZ + ug] : 0.f;
    float h_prev = 0.f;

    const float* gxp = gx + (size_t)bg * G4H + ug;   // + tt*B*4H + p*512
    const int swz = (m16 & 7) << 4;
    int polls = 0;

    float gxc[4];
    #pragma unroll
    for (int p = 0; p < 4; ++p) gxc[p] = gxp[p * H_SZ];

    for (int tt = 0; tt < steps; ++tt) {
        const int t  = t0 + tt;
        const int pb = tt & 1;
        char* dHI = hHI[pb];
        char* dLO = hLO[pb];

        // ---- staging loads + poll (only these sit in the serial vmcnt wait)
        unsigned v[16];
        if (t > 0) {
            const unsigned cexp = ((unsigned)((t - 1) >> 1) & 1u) | 2u;
            const unsigned int* src = hex + ((size_t)((t - 1) & 1) * 4 + grp) * 8192 + tid;
            #pragma unroll
            for (int m = 0; m < 16; ++m)
                v[m] = __hip_atomic_load(src + m * 512, __ATOMIC_RELAXED,
                                         __HIP_MEMORY_SCOPE_AGENT);
            for (;;) {
                bool ok = true;
                #pragma unroll
                for (int m = 0; m < 16; ++m)
                    if ((v[m] & 3u) != cexp) {
                        v[m] = __hip_atomic_load(src + m * 512, __ATOMIC_RELAXED,
                                                 __HIP_MEMORY_SCOPE_AGENT);
                        ok = false;
                    }
                if (ok) break;
                if (++polls > POLL_BUDGET) break;   // hang safety valve
            }
            asm volatile("" ::: "memory");   // pin off-path ops below the poll
        }

        // ---- off-critical-path: h_out(t-1) store, gx(t+1) prefetch
        if (tt > 0)
            h_out[((size_t)bg * T_SZ + (t - 1)) * H_SZ + ug] = h_prev;
        float gxn[4] = {0.f, 0.f, 0.f, 0.f};
        if (tt + 1 < steps) {
            const float* gn = gxp + (size_t)(tt + 1) * (B_SZ * G4H);
            #pragma unroll
            for (int p = 0; p < 4; ++p) gxn[p] = gn[p * H_SZ];
        }

        // ---- stage into swizzled LDS buf[pb]
        if (t == 0) {
            const float4 z = {0.f, 0.f, 0.f, 0.f};
            *(float4*)(dHI + tid * 16)        = z;
            *(float4*)(dHI + tid * 16 + 8192) = z;
            *(float4*)(dLO + tid * 16)        = z;
            *(float4*)(dLO + tid * 16 + 8192) = z;
        } else {
            #pragma unroll
            for (int m = 0; m < 16; ++m) {
                const int off = ((m << 10) + 2 * tid) ^ ((m & 7) << 4);
                *(unsigned short*)(dHI + off) = (unsigned short)(v[m] >> 16);
                *(unsigned short*)(dLO + off) = (unsigned short)(v[m] & 0xFFFCu);
            }
        }
        __syncthreads();   // the ONLY barrier per step

        // ---- 3-product MFMA, full K=512 (2-step WAR safe via barrier order)
        f32x4 a0 = {0.f, 0.f, 0.f, 0.f};
        f32x4 a1 = {0.f, 0.f, 0.f, 0.f};
        f32x4 a2 = {0.f, 0.f, 0.f, 0.f};
        const char* hb = dHI + (m16 << 10);
        const char* lb = dLO + (m16 << 10);
        #pragma unroll
        for (int kk = 0; kk < 16; ++kk) {
            const int off = (kk * 64 + q * 16) ^ swz;
            const short8 hh = *(const short8*)(hb + off);
            const short8 hl = *(const short8*)(lb + off);
            a0 = __builtin_amdgcn_mfma_f32_16x16x32_bf16(whi[kk], hh, a0, 0, 0, 0);
            a1 = __builtin_amdgcn_mfma_f32_16x16x32_bf16(whi[kk], hl, a1, 0, 0, 0);
            a2 = __builtin_amdgcn_mfma_f32_16x16x32_bf16(wlo[kk], hh, a2, 0, 0, 0);
        }

        // ---- in-lane update: acc reg p = gate p for (bg, ug)
        {
            const float gi = a0[0] + a1[0] + a2[0] + gxc[0];
            const float gf = a0[1] + a1[1] + a2[1] + gxc[1];
            const float gc = a0[2] + a1[2] + a2[2] + gxc[2];
            const float go = a0[3] + a1[3] + a2[3] + gxc[3];
            const float si = sigmoid_f(gi);
            const float sf = sigmoid_f(gf);
            const float tc = tanh_f(gc);
            const float so = sigmoid_f(go);
            c_val = sf * c_val + si * tc;
            const float h = so * tanh_f(c_val);
            const unsigned hb16 = f2bf_rne(h);
            const unsigned lb16 = (unsigned)f2bf_rne(h - bf2f((unsigned short)hb16)) & 0xFFFCu;
            const unsigned cb   = ((unsigned)(t >> 1) & 1u) | 2u;
            __hip_atomic_store(hex + ((size_t)(t & 1) * 4 + grp) * 8192 + m16 * 512 + ug,
                               (hb16 << 16) | lb16 | cb,
                               __ATOMIC_RELAXED, __HIP_MEMORY_SCOPE_AGENT);
            h_prev = h;
        }
        #pragma unroll
        for (int p = 0; p < 4; ++p) gxc[p] = gxn[p];
    }
    // deferred last h_out store + cross-chunk c carry
    h_out[((size_t)bg * T_SZ + (t0 + steps - 1)) * H_SZ + ug] = h_prev;
    if (t0 + steps < T_SZ)
        c_state[(size_t)bg * H_SZ + ug] = c_val;
}

// Beacon: surfaces ws_size (MiB) through the absmax error if ws is too small.
__global__ void debug_ws_beacon(float* out, float v)
{
    if (threadIdx.x == 0 && blockIdx.x == 0) out[0] = v;
}

// ---------------------------------------------------------------------------
extern "C" void kernel_launch(void* const* d_in, const int* in_sizes, int n_in,
                              void* d_out, int out_size, void* d_ws, size_t ws_size,
                              hipStream_t stream)
{
    const float* x    = (const float*)d_in[0];
    const float* Wih0 = (const float*)d_in[1];
    const float* Whh0 = (const float*)d_in[2];
    const float* bih0 = (const float*)d_in[3];
    const float* bhh0 = (const float*)d_in[4];
    const float* Wih1 = (const float*)d_in[5];
    const float* Whh1 = (const float*)d_in[6];
    const float* bih1 = (const float*)d_in[7];
    const float* bhh1 = (const float*)d_in[8];
    float* out = (float*)d_out;

    const size_t hexB  = (size_t)2 * 4 * 16 * H_SZ * 4;   // 256 KiB
    const size_t cstB  = (size_t)B_SZ * H_SZ * 4;         // 128 KiB
    const size_t wB    = (size_t)G4H * H_SZ * 2;          // 2 MiB per matrix
    const size_t fixed = hexB + cstB + 4 * wB;

    static const int opts[] = {1536, 768, 512, 384, 256, 128};
    int T_CHUNK = 0;
    for (int i = 0; i < 6; ++i) {
        const size_t need = (size_t)B_SZ * G4H * opts[i] * 4 + fixed;
        if (need <= ws_size) { T_CHUNK = opts[i]; break; }
    }
    if (T_CHUNK == 0) {
        debug_ws_beacon<<<1, 1, 0, stream>>>(out, (float)(ws_size >> 20));
        return;
    }

    char* ws = (char*)d_ws;
    const size_t gxB = (size_t)B_SZ * G4H * T_CHUNK * 4;
    float*          gx      = (float*)ws;
    unsigned int*   hex     = (unsigned int*)(ws + gxB);
    float*          c_state = (float*)(ws + gxB + hexB);
    unsigned short* whi0    = (unsigned short*)(ws + gxB + hexB + cstB);
    unsigned short* wlo0    = whi0 + G4H * H_SZ;
    unsigned short* whi1    = wlo0 + G4H * H_SZ;
    unsigned short* wlo1    = whi1 + G4H * H_SZ;

    const int nW = G4H * H_SZ;
    wsplit<<<(nW + 255) / 256, 256, 0, stream>>>(Whh0, whi0, wlo0, nW);
    wsplit<<<(nW + 255) / 256, 256, 0, stream>>>(Whh1, whi1, wlo1, nW);

    const dim3 ggrid(T_CHUNK / 128, G4H / 128, B_SZ);

    // layer 0
    hipMemsetAsync(hex, 0, hexB, stream);   // cbits bit1=0 -> never valid
    for (int t0 = 0; t0 < T_SZ; t0 += T_CHUNK) {
        gemm_gx<0><<<ggrid, 256, 0, stream>>>(x, Wih0, bih0, bhh0, gx, C_SZ,
                                              C_SZ * T_SZ, t0, T_CHUNK);
        lstm_scan_mfma<<<64, 512, 0, stream>>>(gx, whi0, wlo0, out, hex,
                                               c_state, t0, T_CHUNK, T_CHUNK);
    }
    // layer 1
    hipMemsetAsync(hex, 0, hexB, stream);   // kill layer-0 cbits
    for (int t0 = 0; t0 < T_SZ; t0 += T_CHUNK) {
        gemm_gx<1><<<ggrid, 256, 0, stream>>>(out, Wih1, bih1, bhh1, gx, H_SZ,
                                              T_SZ * H_SZ, t0, T_CHUNK);
        lstm_scan_mfma<<<64, 512, 0, stream>>>(gx, whi1, wlo1, out, hex,
                                               c_state, t0, T_CHUNK, T_CHUNK);
    }
}

// Round 9
// 21524.574 us; speedup vs baseline: 1.0888x; 1.0682x over previous
//
#include <hip/hip_runtime.h>
#include <cstdint>
#include <cstddef>

#define B_SZ 64
#define T_SZ 1536
#define C_SZ 256
#define H_SZ 512
#define G4H  2048
#define POLL_BUDGET 50000000

typedef __attribute__((ext_vector_type(8))) short short8;
typedef __attribute__((ext_vector_type(4))) float f32x4;

__device__ __forceinline__ unsigned short f2bf_rne(float f) {
    unsigned u = __float_as_uint(f);
    unsigned r = (u + 0x7FFF + ((u >> 16) & 1)) >> 16;
    return (unsigned short)r;
}
__device__ __forceinline__ float bf2f(unsigned short b) {
    return __uint_as_float(((unsigned)b) << 16);
}
__device__ __forceinline__ float sigmoid_f(float x) {
    return 1.f / (1.f + __expf(-x));
}
__device__ __forceinline__ float tanh_f(float x) {
    return 1.f - 2.f / (__expf(2.f * x) + 1.f);
}

// ---------------------------------------------------------------------------
// Input GEMM (verified R2-R8). Output [tlen][B][4H].
// ---------------------------------------------------------------------------
template<int AMODE>
__global__ __launch_bounds__(256)
void gemm_gx(const float* __restrict__ A, const float* __restrict__ W,
             const float* __restrict__ bias1, const float* __restrict__ bias2,
             float* __restrict__ gx, int K, int astride_b, int t0g, int tlen)
{
    __shared__ float a_s[8][132];
    __shared__ float b_s[8][132];
    const int tb = blockIdx.x, nb = blockIdx.y, b = blockIdx.z;
    const int tloc = tb * 128;
    const int tglb = t0g + tloc;
    const int r0 = nb * 128;
    const float* Ab = A + (size_t)b * astride_b;
    const int tid = threadIdx.x;
    const int tx = tid & 15, ty = tid >> 4;
    float acc[8][8] = {};

    for (int k0 = 0; k0 < K; k0 += 8) {
        if (AMODE == 0) {
            const int row = tid >> 5;
            const int col = (tid & 31) << 2;
            const float4 v = *(const float4*)(Ab + (size_t)(k0 + row) * T_SZ + tglb + col);
            *(float4*)&a_s[row][col] = v;
        } else {
            const int row  = tid >> 1;
            const int half = (tid & 1) << 2;
            const float4 v = *(const float4*)(Ab + (size_t)(tglb + row) * H_SZ + k0 + half);
            a_s[half + 0][row] = v.x; a_s[half + 1][row] = v.y;
            a_s[half + 2][row] = v.z; a_s[half + 3][row] = v.w;
        }
        {
            const int row  = tid >> 1;
            const int half = (tid & 1) << 2;
            const float4 v = *(const float4*)(W + (size_t)(r0 + row) * K + k0 + half);
            b_s[half + 0][row] = v.x; b_s[half + 1][row] = v.y;
            b_s[half + 2][row] = v.z; b_s[half + 3][row] = v.w;
        }
        __syncthreads();
        #pragma unroll
        for (int kk = 0; kk < 8; ++kk) {
            float4 a0 = *(const float4*)&a_s[kk][tx * 8];
            float4 a1 = *(const float4*)&a_s[kk][tx * 8 + 4];
            float4 w0 = *(const float4*)&b_s[kk][ty * 8];
            float4 w1 = *(const float4*)&b_s[kk][ty * 8 + 4];
            float av[8] = {a0.x, a0.y, a0.z, a0.w, a1.x, a1.y, a1.z, a1.w};
            float wv[8] = {w0.x, w0.y, w0.z, w0.w, w1.x, w1.y, w1.z, w1.w};
            #pragma unroll
            for (int i = 0; i < 8; ++i)
                #pragma unroll
                for (int j = 0; j < 8; ++j)
                    acc[i][j] += wv[i] * av[j];
        }
        __syncthreads();
    }
    float bs[8];
    #pragma unroll
    for (int i = 0; i < 8; ++i)
        bs[i] = bias1[r0 + ty * 8 + i] + bias2[r0 + ty * 8 + i];
    #pragma unroll
    for (int j = 0; j < 8; ++j) {
        float* dst = gx + ((size_t)(tloc + tx * 8 + j) * B_SZ + b) * G4H + r0 + ty * 8;
        float4 o0 = {acc[0][j] + bs[0], acc[1][j] + bs[1], acc[2][j] + bs[2], acc[3][j] + bs[3]};
        float4 o1 = {acc[4][j] + bs[4], acc[5][j] + bs[5], acc[6][j] + bs[6], acc[7][j] + bs[7]};
        *(float4*)dst = o0; *(float4*)(dst + 4) = o1;
    }
}

// ---------------------------------------------------------------------------
__global__ void wsplit(const float* __restrict__ w,
                       unsigned short* __restrict__ hi,
                       unsigned short* __restrict__ lo, int n)
{
    const int i = blockIdx.x * 256 + threadIdx.x;
    if (i < n) {
        const float v = w[i];
        const unsigned short h = f2bf_rne(v);
        hi[i] = h;
        lo[i] = f2bf_rne(v - bf2f(h));
    }
}

// ---------------------------------------------------------------------------
// MFMA LSTM scan v7 = R6 structure (W in AGPRs — NO asm pin; R8 proved the
// pin forces W out of AGPRs and spills) with two levers:
//  * h travels bf16-only in the recurrence (hLO LDS path dropped): per kk
//    ONE ds_read (hh) feeds both products Whi*h + Wlo*h. ds_reads 32->16
//    per wave (~1.5k cy LDS pipe saved/CU/step), staging halves, MFMA
//    48->32. W stays hi/lo so W is fully compensated; only h carries bf16
//    error (~1.7e-4 rms gate error). h_out still stores full fp32 h.
//  * sentinel poll: v[0..15] come from ONE producer store instruction, so
//    spin on v[0] only (4B/thread/iter vs 64B), then batch-reload stragglers.
// Self-validating exchange: u32 = hi<<16 | cbits, cbits = ((t>>1)&1)|2;
// the data load IS the sync (no fences, no L2 flushes).
// Grid = 64 WGs x 512 thr: WG (grp=bid&3: 16 batches, w=bid>>2: 32 units).
// ---------------------------------------------------------------------------
__global__ __launch_bounds__(512, 2)
void lstm_scan_mfma(const float* __restrict__ gx,            // [tlen][B][4H]
                    const unsigned short* __restrict__ Whi,  // [4H][H] bf16 bits
                    const unsigned short* __restrict__ Wlo,
                    float* __restrict__ h_out,               // [B][T][H]
                    unsigned int* hex,                       // [2][4][16][512] u32
                    float* __restrict__ c_state,             // [B][H]
                    int t0, int steps, int tlen)
{
    __shared__ __align__(16) char hHI[2][16384];  // [pb][16 b][512 u] bf16, swizzled

    const int tid  = threadIdx.x;
    const int grp  = blockIdx.x & 3;
    const int w    = blockIdx.x >> 2;     // 0..15
    const int wv   = tid >> 6;            // wave 0..7
    const int lane = tid & 63;
    const int m16  = lane & 15;           // batch col / A-tile row
    const int q    = lane >> 4;           // k-subgroup / unit-in-wave

    // --- W fragments (compiler keeps them in AGPRs across the t-loop):
    // A-tile row r = m16 <-> (gate g = r&3, unit du = r>>2)
    short8 whi[16], wlo[16];
    {
        const size_t rowbase =
            (size_t)((m16 & 3) * H_SZ + w * 32 + wv * 4 + (m16 >> 2)) * H_SZ + q * 8;
        #pragma unroll
        for (int kk = 0; kk < 16; ++kk) {
            whi[kk] = *(const short8*)(Whi + rowbase + kk * 32);
            wlo[kk] = *(const short8*)(Wlo + rowbase + kk * 32);
        }
    }

    // this lane's (batch, unit): C/D col=m16, row=q*4+p <-> gate p, unit q
    const int ug = w * 32 + wv * 4 + q;
    const int bg = grp * 16 + m16;
    float c_val = (t0 > 0) ? c_state[(size_t)bg * H_SZ + ug] : 0.f;
    float h_prev = 0.f;

    const float* gxp = gx + (size_t)bg * G4H + ug;   // + tt*B*4H + p*512
    const int swz = (m16 & 7) << 4;
    int polls = 0;

    float gxc[4];
    #pragma unroll
    for (int p = 0; p < 4; ++p) gxc[p] = gxp[p * H_SZ];

    for (int tt = 0; tt < steps; ++tt) {
        const int t  = t0 + tt;
        const int pb = tt & 1;
        char* dHI = hHI[pb];

        // ---- staging loads + sentinel poll
        unsigned v[16];
        if (t > 0) {
            const unsigned cexp = ((unsigned)((t - 1) >> 1) & 1u) | 2u;
            const unsigned int* src = hex + ((size_t)((t - 1) & 1) * 4 + grp) * 8192 + tid;
            #pragma unroll
            for (int m = 0; m < 16; ++m)
                v[m] = __hip_atomic_load(src + m * 512, __ATOMIC_RELAXED,
                                         __HIP_MEMORY_SCOPE_AGENT);
            for (;;) {
                // spin on the sentinel only (all 16 come from one producer
                // store instruction): 4B/thread/iter instead of 64B
                while ((v[0] & 3u) != cexp) {
                    if (++polls > POLL_BUDGET) break;
                    v[0] = __hip_atomic_load(src, __ATOMIC_RELAXED,
                                             __HIP_MEMORY_SCOPE_AGENT);
                }
                bool ok = true;
                #pragma unroll
                for (int m = 1; m < 16; ++m)
                    if ((v[m] & 3u) != cexp) {
                        v[m] = __hip_atomic_load(src + m * 512, __ATOMIC_RELAXED,
                                                 __HIP_MEMORY_SCOPE_AGENT);
                        ok = false;
                    }
                if (ok || polls > POLL_BUDGET) break;
            }
            asm volatile("" ::: "memory");   // pin off-path ops below the poll
        }

        // ---- off-critical-path: h_out(t-1) store, gx(t+1) prefetch
        if (tt > 0)
            h_out[((size_t)bg * T_SZ + (t - 1)) * H_SZ + ug] = h_prev;
        float gxn[4] = {0.f, 0.f, 0.f, 0.f};
        if (tt + 1 < steps) {
            const float* gn = gxp + (size_t)(tt + 1) * (B_SZ * G4H);
            #pragma unroll
            for (int p = 0; p < 4; ++p) gxn[p] = gn[p * H_SZ];
        }

        // ---- stage into swizzled LDS buf[pb] (hi only)
        if (t == 0) {
            const float4 z = {0.f, 0.f, 0.f, 0.f};
            *(float4*)(dHI + tid * 16)        = z;
            *(float4*)(dHI + tid * 16 + 8192) = z;
        } else {
            #pragma unroll
            for (int m = 0; m < 16; ++m) {
                const int off = ((m << 10) + 2 * tid) ^ ((m & 7) << 4);
                *(unsigned short*)(dHI + off) = (unsigned short)(v[m] >> 16);
            }
        }
        __syncthreads();   // the ONLY barrier per step

        // ---- 2-product MFMA (W hi/lo compensated, h bf16), full K=512
        f32x4 a0 = {0.f, 0.f, 0.f, 0.f};
        f32x4 a2 = {0.f, 0.f, 0.f, 0.f};
        const char* hb = dHI + (m16 << 10);
        #pragma unroll
        for (int kk = 0; kk < 16; ++kk) {
            const int off = (kk * 64 + q * 16) ^ swz;
            const short8 hh = *(const short8*)(hb + off);
            a0 = __builtin_amdgcn_mfma_f32_16x16x32_bf16(whi[kk], hh, a0, 0, 0, 0);
            a2 = __builtin_amdgcn_mfma_f32_16x16x32_bf16(wlo[kk], hh, a2, 0, 0, 0);
        }

        // ---- in-lane update: acc reg p = gate p for (bg, ug)
        {
            const float gi = a0[0] + a2[0] + gxc[0];
            const float gf = a0[1] + a2[1] + gxc[1];
            const float gc = a0[2] + a2[2] + gxc[2];
            const float go = a0[3] + a2[3] + gxc[3];
            const float si = sigmoid_f(gi);
            const float sf = sigmoid_f(gf);
            const float tc = tanh_f(gc);
            const float so = sigmoid_f(go);
            c_val = sf * c_val + si * tc;
            const float h = so * tanh_f(c_val);
            const unsigned hb16 = f2bf_rne(h);
            const unsigned cb   = ((unsigned)(t >> 1) & 1u) | 2u;
            __hip_atomic_store(hex + ((size_t)(t & 1) * 4 + grp) * 8192 + m16 * 512 + ug,
                               (hb16 << 16) | cb,
                               __ATOMIC_RELAXED, __HIP_MEMORY_SCOPE_AGENT);
            h_prev = h;
        }
        #pragma unroll
        for (int p = 0; p < 4; ++p) gxc[p] = gxn[p];
    }
    // deferred last h_out store + cross-chunk c carry
    h_out[((size_t)bg * T_SZ + (t0 + steps - 1)) * H_SZ + ug] = h_prev;
    if (t0 + steps < T_SZ)
        c_state[(size_t)bg * H_SZ + ug] = c_val;
}

// Beacon: surfaces ws_size (MiB) through the absmax error if ws is too small.
__global__ void debug_ws_beacon(float* out, float v)
{
    if (threadIdx.x == 0 && blockIdx.x == 0) out[0] = v;
}

// ---------------------------------------------------------------------------
extern "C" void kernel_launch(void* const* d_in, const int* in_sizes, int n_in,
                              void* d_out, int out_size, void* d_ws, size_t ws_size,
                              hipStream_t stream)
{
    const float* x    = (const float*)d_in[0];
    const float* Wih0 = (const float*)d_in[1];
    const float* Whh0 = (const float*)d_in[2];
    const float* bih0 = (const float*)d_in[3];
    const float* bhh0 = (const float*)d_in[4];
    const float* Wih1 = (const float*)d_in[5];
    const float* Whh1 = (const float*)d_in[6];
    const float* bih1 = (const float*)d_in[7];
    const float* bhh1 = (const float*)d_in[8];
    float* out = (float*)d_out;

    const size_t hexB  = (size_t)2 * 4 * 16 * H_SZ * 4;   // 256 KiB
    const size_t cstB  = (size_t)B_SZ * H_SZ * 4;         // 128 KiB
    const size_t wB    = (size_t)G4H * H_SZ * 2;          // 2 MiB per matrix
    const size_t fixed = hexB + cstB + 4 * wB;

    static const int opts[] = {1536, 768, 512, 384, 256, 128};
    int T_CHUNK = 0;
    for (int i = 0; i < 6; ++i) {
        const size_t need = (size_t)B_SZ * G4H * opts[i] * 4 + fixed;
        if (need <= ws_size) { T_CHUNK = opts[i]; break; }
    }
    if (T_CHUNK == 0) {
        debug_ws_beacon<<<1, 1, 0, stream>>>(out, (float)(ws_size >> 20));
        return;
    }

    char* ws = (char*)d_ws;
    const size_t gxB = (size_t)B_SZ * G4H * T_CHUNK * 4;
    float*          gx      = (float*)ws;
    unsigned int*   hex     = (unsigned int*)(ws + gxB);
    float*          c_state = (float*)(ws + gxB + hexB);
    unsigned short* whi0    = (unsigned short*)(ws + gxB + hexB + cstB);
    unsigned short* wlo0    = whi0 + G4H * H_SZ;
    unsigned short* whi1    = wlo0 + G4H * H_SZ;
    unsigned short* wlo1    = whi1 + G4H * H_SZ;

    const int nW = G4H * H_SZ;
    wsplit<<<(nW + 255) / 256, 256, 0, stream>>>(Whh0, whi0, wlo0, nW);
    wsplit<<<(nW + 255) / 256, 256, 0, stream>>>(Whh1, whi1, wlo1, nW);

    const dim3 ggrid(T_CHUNK / 128, G4H / 128, B_SZ);

    // layer 0
    hipMemsetAsync(hex, 0, hexB, stream);   // cbits bit1=0 -> never valid
    for (int t0 = 0; t0 < T_SZ; t0 += T_CHUNK) {
        gemm_gx<0><<<ggrid, 256, 0, stream>>>(x, Wih0, bih0, bhh0, gx, C_SZ,
                                              C_SZ * T_SZ, t0, T_CHUNK);
        lstm_scan_mfma<<<64, 512, 0, stream>>>(gx, whi0, wlo0, out, hex,
                                               c_state, t0, T_CHUNK, T_CHUNK);
    }
    // layer 1
    hipMemsetAsync(hex, 0, hexB, stream);   // kill layer-0 cbits
    for (int t0 = 0; t0 < T_SZ; t0 += T_CHUNK) {
        gemm_gx<1><<<ggrid, 256, 0, stream>>>(out, Wih1, bih1, bhh1, gx, H_SZ,
                                              T_SZ * H_SZ, t0, T_CHUNK);
        lstm_scan_mfma<<<64, 512, 0, stream>>>(gx, whi1, wlo1, out, hex,
                                               c_state, t0, T_CHUNK, T_CHUNK);
    }
}